// Round 12
// baseline (635.663 us; speedup 1.0000x reference)
//
#include <hip/hip_runtime.h>

// GraphSAGE 2-layer, N=50000, d=128->32->32, E=800000, fp32.
//
// R17: accounting across R12-R16 is inconsistent: solo-measured parts sum to
// ~90-100us but wall is ~162-167 every round. The unowned ~60-70us must be
// inter-dispatch launch/drain + cold-cache first-touch (the harness's 256MiB
// fills wipe L3 between iterations) -- not any kernel body. Fix + decisive
// measurement in one: ONE persistent kernel (1024 blocks = 4/CU guaranteed:
// 256thr, 33.8KB LDS union, launch_bounds(256,4) caps VGPR<=128) with 3
// device-scope grid barriers (release-arrive + acquire-spin, G16 pattern).
// Phases (bodies bit-identical to verified R16 forms, re-shaped to 256thr):
//   P0: blocks*: build chunk bid (784 edges, batched gcnt reserve);
//       blocks<782 then: L1 projection tile -> zl|zr
//   P1: blocks<782: per-bucket counting sort in-place + nod
//   P2: blocks<782: lean gather (proven loop) + relu + W2 -> z2l|z2r
//   P3: all: fagg2 gather -> out (1563 units strided)
// rocprof read: k_all dur = OUR cost; bench-wall minus k_all = harness
// window overhead. Pipeline: memset(gcnt+bar) -> k_all.  (2 dispatches)
// ws: zl|zr|z2l|z2r[N*32] | ebuf[NB*CAPE] | gcnt[NB*32] | bar | nod[N int2]

#define N_NODES 50000
#define NB 782     // buckets = ceil(N/64)
#define BKS 64     // nodes per bucket
#define CAPE 1280  // per-bucket capacity (mean 1023, sd 32; R8-verified)
#define GRID 1024  // 4 blocks/CU x 256 CUs, all co-resident

typedef unsigned int u32;

__device__ __forceinline__ void gridbar(u32* bar, u32 target) {
  __syncthreads();
  if (threadIdx.x == 0) {
    __hip_atomic_fetch_add(bar, 1u, __ATOMIC_RELEASE,
                           __HIP_MEMORY_SCOPE_AGENT);
    while (__hip_atomic_load(bar, __ATOMIC_ACQUIRE,
                             __HIP_MEMORY_SCOPE_AGENT) < target)
      __builtin_amdgcn_s_sleep(16);
  }
  __syncthreads();
}

__global__ __launch_bounds__(256, 4) void k_all(
    const float* __restrict__ x, const int* __restrict__ src,
    const int* __restrict__ dst, const float* __restrict__ W1l,
    const float* __restrict__ b1, const float* __restrict__ W1r,
    const float* __restrict__ W2l, const float* __restrict__ b2,
    const float* __restrict__ W2r, float* __restrict__ zl,
    float* __restrict__ zr, float* __restrict__ z2l,
    float* __restrict__ z2r, int* __restrict__ ebuf, int* __restrict__ gcnt,
    u32* __restrict__ bar, int2* __restrict__ nod, float* __restrict__ out,
    int N, int E) {
  __shared__ __align__(16) union {
    struct { float xs[64 * 68]; float ws[64 * 64]; } p;               // 33.8K
    struct { unsigned pe[800]; int hist[NB]; int cur[NB]; } b;        // 9.5K
    struct { int e[CAPE]; int s[CAPE]; int deg[BKS]; int cur[BKS];
             int off[BKS]; } s;                                        // 11K
    struct { float w2p[32 * 64]; float bsh[32]; float hbuf[BKS * 36]; } f;
  } sm;
  const int t = threadIdx.x;
  const int bid = blockIdx.x;
  const u32 G = gridDim.x;

  // ================= P0a: build (every block, one chunk) ==================
  {
    const int chunk = (((E + GRID - 1) / GRID) + 3) & ~3;  // 784 @ E=800k
    const int e0 = bid * chunk;
    int e1 = e0 + chunk;
    if (e1 > E) e1 = E;
    const int n = e1 - e0;
    if (n > 0) {  // block-uniform
      for (int i = t; i < NB; i += 256) sm.b.hist[i] = 0;
      __syncthreads();
      const int n4 = n >> 2;
      const int4* s4 = (const int4*)(src + e0);
      const int4* d4 = (const int4*)(dst + e0);
      for (int i = t; i < n4; i += 256) {
        int4 sv = s4[i];
        int4 dv = d4[i];
        int4 pk;
        pk.x = (sv.x << 16) | dv.x;
        pk.y = (sv.y << 16) | dv.y;
        pk.z = (sv.z << 16) | dv.z;
        pk.w = (sv.w << 16) | dv.w;
        *(int4*)(sm.b.pe + 4 * i) = pk;
        atomicAdd(&sm.b.hist[dv.x >> 6], 1);
        atomicAdd(&sm.b.hist[dv.y >> 6], 1);
        atomicAdd(&sm.b.hist[dv.z >> 6], 1);
        atomicAdd(&sm.b.hist[dv.w >> 6], 1);
      }
      for (int i = (n4 << 2) + t; i < n; i += 256) {
        unsigned s_ = (unsigned)src[e0 + i];
        unsigned d_ = (unsigned)dst[e0 + i];
        sm.b.pe[i] = (s_ << 16) | d_;
        atomicAdd(&sm.b.hist[d_ >> 6], 1);
      }
      __syncthreads();
      for (int c = t; c < NB; c += 256) {
        int h = sm.b.hist[c];
        sm.b.cur[c] = h ? atomicAdd(&gcnt[c * 32], h) : 0;
      }
      __syncthreads();
      for (int i = t; i < n; i += 256) {
        unsigned pe = sm.b.pe[i];
        int d_ = (int)(pe & 0xFFFFu);
        int s_ = (int)(pe >> 16);
        int c = d_ >> 6;
        int p = atomicAdd(&sm.b.cur[c], 1);
        if (p < CAPE) ebuf[(size_t)c * CAPE + p] = (s_ << 6) | (d_ & 63);
      }
    }
    __syncthreads();  // union switch
  }

  // ========== P0b: L1 projection (blocks < 782, 64 nodes each) ============
  if (bid < (N + 63) / 64) {
    const int K = 128;
    const int n0 = bid * 64;
    const int nvalid = (N - n0) < 64 ? (N - n0) : 64;
    const int tx = t & 15, ty = t >> 4;
    const int c0 = tx * 4;
    const int nl = ty * 4;

    float acc[4][4];
#pragma unroll
    for (int i = 0; i < 4; i++)
#pragma unroll
      for (int j = 0; j < 4; j++) acc[i][j] = 0.f;

    for (int kc = 0; kc < K; kc += 64) {
      for (int i = t; i < 64 * 32; i += 256) {
        int k = i >> 5, c = i & 31;
        sm.p.ws[k * 64 + c] = W1l[(size_t)(kc + k) * 32 + c];
        sm.p.ws[k * 64 + 32 + c] = W1r[(size_t)(kc + k) * 32 + c];
      }
      {
        const int lim = nvalid * 16;
        for (int i = t; i < lim; i += 256) {
          int n = i >> 4, q = i & 15;
          float4 v = *(const float4*)(x + (size_t)(n0 + n) * K + kc + q * 4);
          *(float4*)(sm.p.xs + n * 68 + q * 4) = v;
        }
      }
      __syncthreads();

      const float* x0 = sm.p.xs + (nl + 0) * 68;
      const float* x1 = sm.p.xs + (nl + 1) * 68;
      const float* x2 = sm.p.xs + (nl + 2) * 68;
      const float* x3 = sm.p.xs + (nl + 3) * 68;
      for (int k = 0; k < 64; k += 4) {
        float4 xa = *(const float4*)(x0 + k);
        float4 xb = *(const float4*)(x1 + k);
        float4 xc = *(const float4*)(x2 + k);
        float4 xd = *(const float4*)(x3 + k);
#pragma unroll
        for (int kk = 0; kk < 4; kk++) {
          float4 w = *(const float4*)(sm.p.ws + (k + kk) * 64 + c0);
          float va = ((const float*)&xa)[kk];
          float vb = ((const float*)&xb)[kk];
          float vc = ((const float*)&xc)[kk];
          float vd = ((const float*)&xd)[kk];
          acc[0][0] += va * w.x; acc[0][1] += va * w.y;
          acc[0][2] += va * w.z; acc[0][3] += va * w.w;
          acc[1][0] += vb * w.x; acc[1][1] += vb * w.y;
          acc[1][2] += vb * w.z; acc[1][3] += vb * w.w;
          acc[2][0] += vc * w.x; acc[2][1] += vc * w.y;
          acc[2][2] += vc * w.z; acc[2][3] += vc * w.w;
          acc[3][0] += vd * w.x; acc[3][1] += vd * w.y;
          acc[3][2] += vd * w.z; acc[3][3] += vd * w.w;
        }
      }
      __syncthreads();
    }
#pragma unroll
    for (int i = 0; i < 4; i++) {
      int node = n0 + nl + i;
      if (node < N) {
        float4 v = make_float4(acc[i][0], acc[i][1], acc[i][2], acc[i][3]);
        if (c0 < 32)
          *(float4*)(zl + (size_t)node * 32 + c0) = v;
        else
          *(float4*)(zr + (size_t)node * 32 + (c0 - 32)) = v;
      }
    }
  }

  gridbar(bar, G);

  // ================= P1: per-bucket counting sort =========================
  if (bid < NB) {
    int ne = gcnt[bid * 32];
    if (ne > CAPE) ne = CAPE;
    const size_t base = (size_t)bid * CAPE;
    {
      const int ne4 = ne >> 2;
      const int4* eb4 = (const int4*)(ebuf + base);
      for (int i = t; i < ne4; i += 256) *(int4*)(sm.s.e + 4 * i) = eb4[i];
      for (int i = (ne4 << 2) + t; i < ne; i += 256)
        sm.s.e[i] = ebuf[base + i];
    }
    if (t < BKS) sm.s.deg[t] = 0;
    __syncthreads();
    for (int i = t; i < ne; i += 256) atomicAdd(&sm.s.deg[sm.s.e[i] & 63], 1);
    __syncthreads();
    if (t < 64) {
      int d = sm.s.deg[t];
      int xx = d;
#pragma unroll
      for (int o = 1; o < 64; o <<= 1) {
        int y = __shfl_up(xx, o, 64);
        if (t >= o) xx += y;
      }
      sm.s.off[t] = xx - d;
      sm.s.cur[t] = xx - d;
    }
    __syncthreads();
    for (int i = t; i < ne; i += 256) {
      int v = sm.s.e[i];
      int p = atomicAdd(&sm.s.cur[v & 63], 1);
      sm.s.s[p] = v >> 6;
    }
    __syncthreads();
    for (int i = t; i < ne; i += 256) ebuf[base + i] = sm.s.s[i];
    if (t < BKS) {
      int node = (bid << 6) + t;
      if (node < N) nod[node] = make_int2((int)base + sm.s.off[t], sm.s.deg[t]);
    }
  }

  gridbar(bar, 2 * G);

  // ============ P2: lean gather + relu + W2 proj -> z2l/z2r ===============
  if (bid < NB) {
    for (int i = t; i < 2048; i += 256) {
      int jj = i >> 6, c = i & 63;
      sm.f.w2p[i] = (c < 32) ? W2l[jj * 32 + c] : W2r[jj * 32 + (c - 32)];
    }
    if (t < 32) sm.f.bsh[t] = b1[t];
    __syncthreads();

    const int g = t >> 3, fi = t & 7;
    const float4* zl4 = (const float4*)zl;  // row = 8 float4
#pragma unroll
    for (int half = 0; half < 2; ++half) {
      const int nl = g * 2 + half;
      const int node = (bid << 6) + nl;
      if (node < N) {
        const int2 nd = nod[node];
        float4 acc = make_float4(0.f, 0.f, 0.f, 0.f);
        for (int b0 = 0; b0 < nd.y; b0 += 8) {
          const int myi = b0 + fi;
          int sidx = (myi < nd.y) ? ebuf[nd.x + myi] : 0;
#pragma unroll
          for (int q = 0; q < 8; q++) {
            if (b0 + q < nd.y) {
              int s_ = __shfl(sidx, q, 8);
              float4 f = zl4[(size_t)s_ * 8 + fi];
              acc.x += f.x; acc.y += f.y; acc.z += f.z; acc.w += f.w;
            }
          }
        }
        const float rd = 1.0f / (float)(nd.y > 1 ? nd.y : 1);
        const float4 b4 = *(const float4*)(sm.f.bsh + fi * 4);
        const float4 sA = *(const float4*)(zr + (size_t)node * 32 + fi * 4);
        float4 h;
        h.x = fmaxf(acc.x * rd + b4.x + sA.x, 0.f);
        h.y = fmaxf(acc.y * rd + b4.y + sA.y, 0.f);
        h.z = fmaxf(acc.z * rd + b4.z + sA.z, 0.f);
        h.w = fmaxf(acc.w * rd + b4.w + sA.w, 0.f);
        *(float4*)(sm.f.hbuf + nl * 36 + fi * 4) = h;
      }
    }
    __syncthreads();

    const int gg = t >> 5, j = t & 31;
    const int n0 = bid << 6;
#pragma unroll
    for (int i = 0; i < 8; i++) {
      const int nl = gg * 8 + i;
      const int nodei = n0 + nl;
      if (nodei >= N) break;
      const float h = sm.f.hbuf[nl * 36 + j];
      float p0 = 0.f, p1 = 0.f;
#pragma unroll
      for (int jj = 0; jj < 32; jj++) {
        float hj = __shfl(h, jj, 32);
        p0 += hj * sm.f.w2p[jj * 64 + j];
        p1 += hj * sm.f.w2p[jj * 64 + 32 + j];
      }
      z2l[(size_t)nodei * 32 + j] = p0;
      z2r[(size_t)nodei * 32 + j] = p1;
    }
  }

  gridbar(bar, 3 * G);

  // =================== P3: fagg2 gather -> out ============================
  {
    const int g = t >> 3, fi = t & 7;
    const float4* z24 = (const float4*)z2l;
    const float4 b4 = *(const float4*)(b2 + fi * 4);
    for (int v = bid; v < (N + 31) / 32; v += (int)G) {
      const int node = v * 32 + g;
      if (node < N) {
        const int2 nd = nod[node];
        float4 acc = make_float4(0.f, 0.f, 0.f, 0.f);
        for (int b0 = 0; b0 < nd.y; b0 += 8) {
          const int myi = b0 + fi;
          int sidx = (myi < nd.y) ? ebuf[nd.x + myi] : 0;
#pragma unroll
          for (int q = 0; q < 8; q++) {
            if (b0 + q < nd.y) {
              int s_ = __shfl(sidx, q, 8);
              float4 f = z24[(size_t)s_ * 8 + fi];
              acc.x += f.x; acc.y += f.y; acc.z += f.z; acc.w += f.w;
            }
          }
        }
        const float rd = 1.0f / (float)(nd.y > 1 ? nd.y : 1);
        const float4 sB = *(const float4*)(z2r + (size_t)node * 32 + fi * 4);
        float4 o;
        o.x = acc.x * rd + b4.x + sB.x;
        o.y = acc.y * rd + b4.y + sB.y;
        o.z = acc.z * rd + b4.z + sB.z;
        o.w = acc.w * rd + b4.w + sB.w;
        *(float4*)(out + (size_t)node * 32 + fi * 4) = o;
      }
    }
  }
}

extern "C" void kernel_launch(void* const* d_in, const int* in_sizes, int n_in,
                              void* d_out, int out_size, void* d_ws,
                              size_t ws_size, hipStream_t stream) {
  const float* x = (const float*)d_in[0];
  const int* ei = (const int*)d_in[1];  // int32 (harness narrows int64)
  const float* W1l = (const float*)d_in[2];
  const float* b1 = (const float*)d_in[3];
  const float* W1r = (const float*)d_in[4];
  const float* W2l = (const float*)d_in[5];
  const float* b2 = (const float*)d_in[6];
  const float* W2r = (const float*)d_in[7];
  float* out = (float*)d_out;

  const int N = N_NODES;
  const int E = in_sizes[1] / 2;  // 800000

  float* zl = (float*)d_ws;                    // N*32
  float* zr = zl + (size_t)N * 32;             // N*32
  float* z2l = zr + (size_t)N * 32;            // N*32
  float* z2r = z2l + (size_t)N * 32;           // N*32
  int* ebuf = (int*)(z2r + (size_t)N * 32);    // NB*CAPE
  int* gcnt = ebuf + (size_t)NB * CAPE;        // NB*32
  u32* bar = (u32*)(gcnt + (size_t)NB * 32);   // 1 (+pad 8)
  int2* nod = (int2*)(bar + 8);                // N

  const int* srcp = ei;
  const int* dstp = ei + E;

  hipMemsetAsync(gcnt, 0, ((size_t)NB * 32 + 8) * sizeof(int), stream);
  k_all<<<GRID, 256, 0, stream>>>(x, srcp, dstp, W1l, b1, W1r, W2l, b2, W2r,
                                  zl, zr, z2l, z2r, ebuf, gcnt, bar, nod, out,
                                  N, E);
}

// Round 13
// 164.405 us; speedup vs baseline: 3.8664x; 3.8664x over previous
//
#include <hip/hip_runtime.h>

// GraphSAGE 2-layer, N=50000, d=128->32->32, E=800000, fp32.
//
// R18: R17 persistent kernel failed (agent-scope grid barriers force
// per-XCD L2 flush: 585us GPU). Accounting is closed: wall = kernels(75) +
// ~87us fixed harness fills. Inside kernels, fagg1's counting sort is ~20us
// of LDS-op throughput (4 LDS passes x 1024 edges/block). Fix: FIXED-SLOT
// scatter -- node nl owns slots [nl*48,nl*48+48) in its bucket (Poisson16:
// P(deg>=48)~1e-11 -> never hit; clamped). One pass: read ebuf -> LDS
// atomic cur[d] -> write slot LDS + ebuf2 global. Deletes staging, count,
// scan, write-back passes + 2 barriers. Gather/W2/fagg2 unchanged
// (fagg2 reads ebuf2 via nod).
// Pipeline: memset(gcnt) -> k_front(build||projL1) ->
//           k_fagg1(slot-scatter+gather+relu+W2 -> z2l/z2r, nod/ebuf2) ->
//           k_fagg2(-> out).
// ws: zl|zr|z2l|z2r[N*32] | ebuf[NB*CAPE] | ebuf2[NB*3072] | gcnt[NB*32] |
//     nod[N int2]   (~40MB)

#define N_NODES 50000
#define NB 782     // buckets = ceil(N/64)
#define BKS 64     // nodes per bucket
#define GB 256     // build blocks
#define CAPE 1280  // per-bucket capacity (mean 1023, sd 32; R8-verified)
#define CAPN 48    // per-node slot capacity (Poisson(16): P(>=48)~1e-11)
#define TILE 3200  // build LDS staging tile (chunk=3128 fits in one)

// ---- k_front: build (blocks < GB) + L1 projection (blocks >= GB) ---------
__global__ __launch_bounds__(256) void k_front(
    const float* __restrict__ in, const float* __restrict__ Wl,
    const float* __restrict__ Wr, float* __restrict__ zl,
    float* __restrict__ zr, int N, int K, const int* __restrict__ src,
    const int* __restrict__ dst, int* __restrict__ gcnt,
    int* __restrict__ ebuf, int E) {
  __shared__ __align__(16) union {
    struct { float xs[64 * 68]; float ws[64 * 64]; } p;          // 33.8 KB
    struct { unsigned pe[TILE]; int hist[NB]; int cur[NB]; } b;  // 19.1 KB
  } sm;
  const int t = threadIdx.x;

  if (blockIdx.x < GB) {
    // ---------------- build role ----------------
    const int chunk = (((E + GB - 1) / GB) + 3) & ~3;  // 3128: 16B-aligned e0
    const int e0 = blockIdx.x * chunk;
    int e1 = e0 + chunk;
    if (e1 > E) e1 = E;
    for (int ts = e0; ts < e1; ts += TILE) {
      int te = ts + TILE;
      if (te > e1) te = e1;
      const int n = te - ts;
      if (n <= 0) break;
      for (int i = t; i < NB; i += 256) sm.b.hist[i] = 0;
      __syncthreads();
      {
        const int n4 = n >> 2;
        const int4* s4 = (const int4*)(src + ts);
        const int4* d4 = (const int4*)(dst + ts);
        for (int i = t; i < n4; i += 256) {
          int4 sv = s4[i];
          int4 dv = d4[i];
          int4 pk;
          pk.x = (sv.x << 16) | dv.x;
          pk.y = (sv.y << 16) | dv.y;
          pk.z = (sv.z << 16) | dv.z;
          pk.w = (sv.w << 16) | dv.w;
          *(int4*)(sm.b.pe + 4 * i) = pk;
          atomicAdd(&sm.b.hist[dv.x >> 6], 1);
          atomicAdd(&sm.b.hist[dv.y >> 6], 1);
          atomicAdd(&sm.b.hist[dv.z >> 6], 1);
          atomicAdd(&sm.b.hist[dv.w >> 6], 1);
        }
        for (int i = (n4 << 2) + t; i < n; i += 256) {
          unsigned s = (unsigned)src[ts + i];
          unsigned d = (unsigned)dst[ts + i];
          sm.b.pe[i] = (s << 16) | d;
          atomicAdd(&sm.b.hist[d >> 6], 1);
        }
      }
      __syncthreads();
      for (int c = t; c < NB; c += 256) {
        int h = sm.b.hist[c];
        sm.b.cur[c] = h ? atomicAdd(&gcnt[c * 32], h) : 0;  // padded line/bkt
      }
      __syncthreads();
      for (int i = t; i < n; i += 256) {
        unsigned pe = sm.b.pe[i];
        int d = (int)(pe & 0xFFFFu);
        int s = (int)(pe >> 16);
        int c = d >> 6;
        int p = atomicAdd(&sm.b.cur[c], 1);
        if (p < CAPE) ebuf[(size_t)c * CAPE + p] = (s << 6) | (d & 63);
      }
      __syncthreads();
    }
    return;
  }

  // ------- projection role: zl[n][0:32)=in@Wl, zr[n][0:32)=in@Wr ----------
  const int n0 = (blockIdx.x - GB) * 64;
  const int nvalid = (N - n0) < 64 ? (N - n0) : 64;
  const int tx = t & 15, ty = t >> 4;
  const int c0 = tx * 4;
  const int nl = ty * 4;

  float acc[4][4];
#pragma unroll
  for (int i = 0; i < 4; i++)
#pragma unroll
    for (int j = 0; j < 4; j++) acc[i][j] = 0.f;

  for (int kc = 0; kc < K; kc += 64) {
    const int KC = (K - kc) < 64 ? (K - kc) : 64;
    for (int i = t; i < KC * 32; i += 256) {
      int k = i >> 5, c = i & 31;
      sm.p.ws[k * 64 + c] = Wl[(size_t)(kc + k) * 32 + c];
      sm.p.ws[k * 64 + 32 + c] = Wr[(size_t)(kc + k) * 32 + c];
    }
    {
      const int kq = KC >> 2;
      const int sh = (KC == 64) ? 4 : 3;
      const int lim = nvalid * kq;
      for (int i = t; i < lim; i += 256) {
        int n = i >> sh, q = i & (kq - 1);
        float4 v = *(const float4*)(in + (size_t)(n0 + n) * K + kc + q * 4);
        *(float4*)(sm.p.xs + n * 68 + q * 4) = v;
      }
    }
    __syncthreads();

    const float* x0 = sm.p.xs + (nl + 0) * 68;
    const float* x1 = sm.p.xs + (nl + 1) * 68;
    const float* x2 = sm.p.xs + (nl + 2) * 68;
    const float* x3 = sm.p.xs + (nl + 3) * 68;
    for (int k = 0; k < KC; k += 4) {
      float4 xa = *(const float4*)(x0 + k);
      float4 xb = *(const float4*)(x1 + k);
      float4 xc = *(const float4*)(x2 + k);
      float4 xd = *(const float4*)(x3 + k);
#pragma unroll
      for (int kk = 0; kk < 4; kk++) {
        float4 w = *(const float4*)(sm.p.ws + (k + kk) * 64 + c0);
        float va = ((const float*)&xa)[kk];
        float vb = ((const float*)&xb)[kk];
        float vc = ((const float*)&xc)[kk];
        float vd = ((const float*)&xd)[kk];
        acc[0][0] += va * w.x; acc[0][1] += va * w.y;
        acc[0][2] += va * w.z; acc[0][3] += va * w.w;
        acc[1][0] += vb * w.x; acc[1][1] += vb * w.y;
        acc[1][2] += vb * w.z; acc[1][3] += vb * w.w;
        acc[2][0] += vc * w.x; acc[2][1] += vc * w.y;
        acc[2][2] += vc * w.z; acc[2][3] += vc * w.w;
        acc[3][0] += vd * w.x; acc[3][1] += vd * w.y;
        acc[3][2] += vd * w.z; acc[3][3] += vd * w.w;
      }
    }
    __syncthreads();
  }
#pragma unroll
  for (int i = 0; i < 4; i++) {
    int node = n0 + nl + i;
    if (node < N) {
      float4 v = make_float4(acc[i][0], acc[i][1], acc[i][2], acc[i][3]);
      if (c0 < 32)
        *(float4*)(zl + (size_t)node * 32 + c0) = v;
      else
        *(float4*)(zr + (size_t)node * 32 + (c0 - 32)) = v;
    }
  }
}

// ---- fused L1: fixed-slot scatter + gather + relu + W2 -> z2l/z2r --------
// 512 thr. Scatter: one pass, 1 LDS atomic + 1 LDS write + 1 global write
// per edge (no staging/count/scan/write-back). Gather: proven 8-lane MLP
// loop over slot[]. Emits nod + ebuf2 (fixed-slot adj) for fagg2.
__global__ __launch_bounds__(512) void k_fagg1(
    const float* __restrict__ zl, const float* __restrict__ zr,
    const int* __restrict__ ebuf, const int* __restrict__ gcnt,
    const float* __restrict__ b1, const float* __restrict__ W2l,
    const float* __restrict__ W2r, float* __restrict__ z2l,
    float* __restrict__ z2r, int* __restrict__ ebuf2,
    int2* __restrict__ nod, int N) {
  __shared__ int slot[BKS * CAPN];  // 12 KB
  __shared__ int cur[BKS];
  __shared__ float w2p[32 * 64];    // 8 KB
  __shared__ __align__(16) float bsh[32];
  __shared__ __align__(16) float hbuf[BKS * 36];  // 9 KB
  const int t = threadIdx.x;
  const int k = blockIdx.x;
  int ne = gcnt[k * 32];
  if (ne > CAPE) ne = CAPE;
  const size_t base = (size_t)k * CAPE;
  const int base2 = k * (BKS * CAPN);

  for (int i = t; i < 2048; i += 512) {
    int jj = i >> 6, c = i & 63;
    w2p[i] = (c < 32) ? W2l[jj * 32 + c] : W2r[jj * 32 + (c - 32)];
  }
  if (t < 32) bsh[t] = b1[t];
  if (t < BKS) cur[t] = 0;
  __syncthreads();

  // one-pass scatter
  for (int i = t; i < ne; i += 512) {
    int v = ebuf[base + i];
    int d = v & 63, s = v >> 6;
    int c = atomicAdd(&cur[d], 1);
    if (c < CAPN) {
      slot[d * CAPN + c] = s;
      ebuf2[base2 + d * CAPN + c] = s;
    }
  }
  __syncthreads();

  if (t < BKS) {
    int node = (k << 6) + t;
    if (node < N) {
      int dg = cur[t] < CAPN ? cur[t] : CAPN;
      nod[node] = make_int2(base2 + t * CAPN, dg);
    }
  }

  // gather: 8-lane group g owns node g; 8 chains in flight per group
  const int g = t >> 3, fi = t & 7;
  const int node = (k << 6) + g;
  {
    int dg = cur[g] < CAPN ? cur[g] : CAPN;
    const float4* zl4 = (const float4*)zl;  // row = 8 float4
    float4 acc = make_float4(0.f, 0.f, 0.f, 0.f);
    const int a = g * CAPN;
    for (int b0 = 0; b0 < dg; b0 += 8) {
      const int myi = b0 + fi;
      int sidx = (myi < dg) ? slot[a + myi] : 0;
#pragma unroll
      for (int q = 0; q < 8; q++) {
        if (b0 + q < dg) {
          int s = __shfl(sidx, q, 8);
          float4 f = zl4[(size_t)s * 8 + fi];
          acc.x += f.x; acc.y += f.y; acc.z += f.z; acc.w += f.w;
        }
      }
    }
    if (node < N) {
      const float rd = 1.0f / (float)(dg > 1 ? dg : 1);
      const float4 b4 = *(const float4*)(bsh + fi * 4);
      const float4 sA = *(const float4*)(zr + (size_t)node * 32 + fi * 4);
      float4 h;
      h.x = fmaxf(acc.x * rd + b4.x + sA.x, 0.f);
      h.y = fmaxf(acc.y * rd + b4.y + sA.y, 0.f);
      h.z = fmaxf(acc.z * rd + b4.z + sA.z, 0.f);
      h.w = fmaxf(acc.w * rd + b4.w + sA.w, 0.f);
      *(float4*)(hbuf + g * 36 + fi * 4) = h;
    }
  }
  __syncthreads();

  // W2 mini-GEMM: 16 groups of 32 lanes, group gg -> nodes gg*4..+3
  const int gg = t >> 5, j = t & 31;
  const int n0 = k << 6;
#pragma unroll
  for (int i = 0; i < 4; i++) {
    const int nl = gg * 4 + i;
    const int nodei = n0 + nl;
    if (nodei >= N) break;
    const float h = hbuf[nl * 36 + j];
    float p0 = 0.f, p1 = 0.f;
#pragma unroll
    for (int jj = 0; jj < 32; jj++) {
      float hj = __shfl(h, jj, 32);
      p0 += hj * w2p[jj * 64 + j];
      p1 += hj * w2p[jj * 64 + 32 + j];
    }
    z2l[(size_t)nodei * 32 + j] = p0;
    z2r[(size_t)nodei * 32 + j] = p1;
  }
}

// ---- fused L2: lean LDS-free gather -> out -------------------------------
__global__ __launch_bounds__(256) void k_fagg2(
    const float* __restrict__ z2l, const float* __restrict__ z2r,
    const int* __restrict__ adj, const int2* __restrict__ nod,
    const float* __restrict__ b2, float* __restrict__ out, int N) {
  __shared__ __align__(16) float bsh[32];
  const int t = threadIdx.x;
  if (t < 32) bsh[t] = b2[t];
  __syncthreads();
  const int g = t >> 3, fi = t & 7;
  const int node = blockIdx.x * 32 + g;
  if (node >= N) return;
  const int2 nd = nod[node];
  const float4* z24 = (const float4*)z2l;
  float4 acc = make_float4(0.f, 0.f, 0.f, 0.f);
  for (int b0 = 0; b0 < nd.y; b0 += 8) {
    const int myi = b0 + fi;
    int sidx = (myi < nd.y) ? adj[nd.x + myi] : 0;
#pragma unroll
    for (int q = 0; q < 8; q++) {
      if (b0 + q < nd.y) {
        int s = __shfl(sidx, q, 8);
        float4 f = z24[(size_t)s * 8 + fi];
        acc.x += f.x; acc.y += f.y; acc.z += f.z; acc.w += f.w;
      }
    }
  }
  const float rd = 1.0f / (float)(nd.y > 1 ? nd.y : 1);
  const float4 b4 = *(const float4*)(bsh + fi * 4);
  const float4 sB = *(const float4*)(z2r + (size_t)node * 32 + fi * 4);
  float4 o;
  o.x = acc.x * rd + b4.x + sB.x;
  o.y = acc.y * rd + b4.y + sB.y;
  o.z = acc.z * rd + b4.z + sB.z;
  o.w = acc.w * rd + b4.w + sB.w;
  *(float4*)(out + (size_t)node * 32 + fi * 4) = o;
}

extern "C" void kernel_launch(void* const* d_in, const int* in_sizes, int n_in,
                              void* d_out, int out_size, void* d_ws,
                              size_t ws_size, hipStream_t stream) {
  const float* x = (const float*)d_in[0];
  const int* ei = (const int*)d_in[1];  // int32 (harness narrows int64)
  const float* W1l = (const float*)d_in[2];
  const float* b1 = (const float*)d_in[3];
  const float* W1r = (const float*)d_in[4];
  const float* W2l = (const float*)d_in[5];
  const float* b2 = (const float*)d_in[6];
  const float* W2r = (const float*)d_in[7];
  float* out = (float*)d_out;

  const int N = N_NODES;
  const int E = in_sizes[1] / 2;  // 800000

  float* zl = (float*)d_ws;                    // N*32
  float* zr = zl + (size_t)N * 32;             // N*32
  float* z2l = zr + (size_t)N * 32;            // N*32
  float* z2r = z2l + (size_t)N * 32;           // N*32
  int* ebuf = (int*)(z2r + (size_t)N * 32);    // NB*CAPE
  int* ebuf2 = ebuf + (size_t)NB * CAPE;       // NB*BKS*CAPN (~9.6MB)
  int* gcnt = ebuf2 + (size_t)NB * BKS * CAPN; // NB*32
  int2* nod = (int2*)(gcnt + (size_t)NB * 32); // N

  const int* srcp = ei;
  const int* dstp = ei + E;

  const int nblk_proj = (N + 63) / 64;  // 782
  const int nblk_f2 = (N + 31) / 32;    // 1563

  hipMemsetAsync(gcnt, 0, (size_t)NB * 32 * sizeof(int), stream);
  k_front<<<GB + nblk_proj, 256, 0, stream>>>(x, W1l, W1r, zl, zr, N, 128,
                                              srcp, dstp, gcnt, ebuf, E);
  k_fagg1<<<NB, 512, 0, stream>>>(zl, zr, ebuf, gcnt, b1, W2l, W2r, z2l, z2r,
                                  ebuf2, nod, N);
  k_fagg2<<<nblk_f2, 256, 0, stream>>>(z2l, z2r, ebuf2, nod, b2, out, N);
}

// Round 14
// 160.257 us; speedup vs baseline: 3.9665x; 1.0259x over previous
//
#include <hip/hip_runtime.h>

// GraphSAGE 2-layer, N=50000, d=128->32->32, E=800000, fp32.
//
// R19: sort-family ablation closed (full/split/one-pass all ~162-167 =>
// sort was never 20us). Re-derivation: fagg1(45) vs fagg2(6.4) gap is the
// fused W2 mini-GEMM's __shfl loop -- __shfl = ds_bpermute = LDS-pipe op.
// 4nodes x 32jj x 3 LDS-ops x 8 waves x 3 blk/CU ~ 56k cy ~ 23us of
// serialized LDS pipe. Fix: un-fuse. kproj2 = proven R4 LDS-tiled GEMM
// (K=32, VALU-bound, ~4us). fagg1 = clone of the proven 6.4us fagg2 loop
// (+relu, self=zr) -> h in d_out scratch (R5-style). Sort = R16's k_sort.
// Pipeline: memset -> k_front(build||proj1) -> k_sort -> k_fagg1(->h) ->
//           kproj2(h->z2l|z2r) -> k_fagg2(->out).
// ws: zl|zr|z2l|z2r[N*32] | ebuf[NB*CAPE] | gcnt[NB*32] | nod[N int2]

#define N_NODES 50000
#define NB 782     // buckets = ceil(N/64)
#define BKS 64     // nodes per bucket
#define GB 256     // build blocks
#define CAPE 1280  // per-bucket capacity (mean 1023, sd 32; R8-verified)
#define TILE 3200  // build LDS staging tile (chunk=3128 fits in one)

// ---- k_front: build (blocks < GB) + L1 projection (blocks >= GB) ---------
__global__ __launch_bounds__(256) void k_front(
    const float* __restrict__ in, const float* __restrict__ Wl,
    const float* __restrict__ Wr, float* __restrict__ zl,
    float* __restrict__ zr, int N, int K, const int* __restrict__ src,
    const int* __restrict__ dst, int* __restrict__ gcnt,
    int* __restrict__ ebuf, int E) {
  __shared__ __align__(16) union {
    struct { float xs[64 * 68]; float ws[64 * 64]; } p;          // 33.8 KB
    struct { unsigned pe[TILE]; int hist[NB]; int cur[NB]; } b;  // 19.1 KB
  } sm;
  const int t = threadIdx.x;

  if (blockIdx.x < GB) {
    // ---------------- build role ----------------
    const int chunk = (((E + GB - 1) / GB) + 3) & ~3;  // 3128: 16B-aligned e0
    const int e0 = blockIdx.x * chunk;
    int e1 = e0 + chunk;
    if (e1 > E) e1 = E;
    for (int ts = e0; ts < e1; ts += TILE) {
      int te = ts + TILE;
      if (te > e1) te = e1;
      const int n = te - ts;
      if (n <= 0) break;
      for (int i = t; i < NB; i += 256) sm.b.hist[i] = 0;
      __syncthreads();
      {
        const int n4 = n >> 2;
        const int4* s4 = (const int4*)(src + ts);
        const int4* d4 = (const int4*)(dst + ts);
        for (int i = t; i < n4; i += 256) {
          int4 sv = s4[i];
          int4 dv = d4[i];
          int4 pk;
          pk.x = (sv.x << 16) | dv.x;
          pk.y = (sv.y << 16) | dv.y;
          pk.z = (sv.z << 16) | dv.z;
          pk.w = (sv.w << 16) | dv.w;
          *(int4*)(sm.b.pe + 4 * i) = pk;
          atomicAdd(&sm.b.hist[dv.x >> 6], 1);
          atomicAdd(&sm.b.hist[dv.y >> 6], 1);
          atomicAdd(&sm.b.hist[dv.z >> 6], 1);
          atomicAdd(&sm.b.hist[dv.w >> 6], 1);
        }
        for (int i = (n4 << 2) + t; i < n; i += 256) {
          unsigned s = (unsigned)src[ts + i];
          unsigned d = (unsigned)dst[ts + i];
          sm.b.pe[i] = (s << 16) | d;
          atomicAdd(&sm.b.hist[d >> 6], 1);
        }
      }
      __syncthreads();
      for (int c = t; c < NB; c += 256) {
        int h = sm.b.hist[c];
        sm.b.cur[c] = h ? atomicAdd(&gcnt[c * 32], h) : 0;  // padded line/bkt
      }
      __syncthreads();
      for (int i = t; i < n; i += 256) {
        unsigned pe = sm.b.pe[i];
        int d = (int)(pe & 0xFFFFu);
        int s = (int)(pe >> 16);
        int c = d >> 6;
        int p = atomicAdd(&sm.b.cur[c], 1);
        if (p < CAPE) ebuf[(size_t)c * CAPE + p] = (s << 6) | (d & 63);
      }
      __syncthreads();
    }
    return;
  }

  // ------- projection role: zl[n][0:32)=in@Wl, zr[n][0:32)=in@Wr ----------
  const int n0 = (blockIdx.x - GB) * 64;
  const int nvalid = (N - n0) < 64 ? (N - n0) : 64;
  const int tx = t & 15, ty = t >> 4;
  const int c0 = tx * 4;
  const int nl = ty * 4;

  float acc[4][4];
#pragma unroll
  for (int i = 0; i < 4; i++)
#pragma unroll
    for (int j = 0; j < 4; j++) acc[i][j] = 0.f;

  for (int kc = 0; kc < K; kc += 64) {
    const int KC = (K - kc) < 64 ? (K - kc) : 64;
    for (int i = t; i < KC * 32; i += 256) {
      int k = i >> 5, c = i & 31;
      sm.p.ws[k * 64 + c] = Wl[(size_t)(kc + k) * 32 + c];
      sm.p.ws[k * 64 + 32 + c] = Wr[(size_t)(kc + k) * 32 + c];
    }
    {
      const int kq = KC >> 2;
      const int sh = (KC == 64) ? 4 : 3;
      const int lim = nvalid * kq;
      for (int i = t; i < lim; i += 256) {
        int n = i >> sh, q = i & (kq - 1);
        float4 v = *(const float4*)(in + (size_t)(n0 + n) * K + kc + q * 4);
        *(float4*)(sm.p.xs + n * 68 + q * 4) = v;
      }
    }
    __syncthreads();

    const float* x0 = sm.p.xs + (nl + 0) * 68;
    const float* x1 = sm.p.xs + (nl + 1) * 68;
    const float* x2 = sm.p.xs + (nl + 2) * 68;
    const float* x3 = sm.p.xs + (nl + 3) * 68;
    for (int k = 0; k < KC; k += 4) {
      float4 xa = *(const float4*)(x0 + k);
      float4 xb = *(const float4*)(x1 + k);
      float4 xc = *(const float4*)(x2 + k);
      float4 xd = *(const float4*)(x3 + k);
#pragma unroll
      for (int kk = 0; kk < 4; kk++) {
        float4 w = *(const float4*)(sm.p.ws + (k + kk) * 64 + c0);
        float va = ((const float*)&xa)[kk];
        float vb = ((const float*)&xb)[kk];
        float vc = ((const float*)&xc)[kk];
        float vd = ((const float*)&xd)[kk];
        acc[0][0] += va * w.x; acc[0][1] += va * w.y;
        acc[0][2] += va * w.z; acc[0][3] += va * w.w;
        acc[1][0] += vb * w.x; acc[1][1] += vb * w.y;
        acc[1][2] += vb * w.z; acc[1][3] += vb * w.w;
        acc[2][0] += vc * w.x; acc[2][1] += vc * w.y;
        acc[2][2] += vc * w.z; acc[2][3] += vc * w.w;
        acc[3][0] += vd * w.x; acc[3][1] += vd * w.y;
        acc[3][2] += vd * w.z; acc[3][3] += vd * w.w;
      }
    }
    __syncthreads();
  }
#pragma unroll
  for (int i = 0; i < 4; i++) {
    int node = n0 + nl + i;
    if (node < N) {
      float4 v = make_float4(acc[i][0], acc[i][1], acc[i][2], acc[i][3]);
      if (c0 < 32)
        *(float4*)(zl + (size_t)node * 32 + c0) = v;
      else
        *(float4*)(zr + (size_t)node * 32 + (c0 - 32)) = v;
    }
  }
}

// ---- k_sort: per-bucket counting sort (in-place) + nod -------------------
__global__ __launch_bounds__(256) void k_sort(int* __restrict__ ebuf,
                                              const int* __restrict__ gcnt,
                                              int2* __restrict__ nod, int N) {
  __shared__ __align__(16) int lds_e[CAPE];
  __shared__ int lds_s[CAPE];
  __shared__ int deg[BKS];
  __shared__ int cur[BKS];
  __shared__ int off[BKS];
  const int t = threadIdx.x;
  const int k = blockIdx.x;
  int ne = gcnt[k * 32];
  if (ne > CAPE) ne = CAPE;  // statistically never hit; memory-safety clamp
  const size_t base = (size_t)k * CAPE;

  {
    const int ne4 = ne >> 2;
    const int4* eb4 = (const int4*)(ebuf + base);
    for (int i = t; i < ne4; i += 256) *(int4*)(lds_e + 4 * i) = eb4[i];
    for (int i = (ne4 << 2) + t; i < ne; i += 256) lds_e[i] = ebuf[base + i];
  }
  if (t < BKS) deg[t] = 0;
  __syncthreads();
  for (int i = t; i < ne; i += 256) atomicAdd(&deg[lds_e[i] & 63], 1);
  __syncthreads();
  if (t < 64) {
    int d = deg[t];
    int x = d;
#pragma unroll
    for (int o = 1; o < 64; o <<= 1) {
      int y = __shfl_up(x, o, 64);
      if (t >= o) x += y;
    }
    off[t] = x - d;
    cur[t] = x - d;
  }
  __syncthreads();
  for (int i = t; i < ne; i += 256) {
    int v = lds_e[i];
    int p = atomicAdd(&cur[v & 63], 1);
    lds_s[p] = v >> 6;
  }
  __syncthreads();
  for (int i = t; i < ne; i += 256) ebuf[base + i] = lds_s[i];  // in-place
  if (t < BKS) {
    int node = (k << 6) + t;
    if (node < N) nod[node] = make_int2((int)base + off[t], deg[t]);
  }
}

// ---- k_fagg1: lean gather + relu -> h (clone of proven fagg2 loop) -------
__global__ __launch_bounds__(256) void k_fagg1(
    const float* __restrict__ zl, const float* __restrict__ zr,
    const int* __restrict__ adj, const int2* __restrict__ nod,
    const float* __restrict__ b1, float* __restrict__ h, int N) {
  __shared__ __align__(16) float bsh[32];
  const int t = threadIdx.x;
  if (t < 32) bsh[t] = b1[t];
  __syncthreads();
  const int g = t >> 3, fi = t & 7;
  const int node = blockIdx.x * 32 + g;
  if (node >= N) return;
  const int2 nd = nod[node];
  const float4* zl4 = (const float4*)zl;
  float4 acc = make_float4(0.f, 0.f, 0.f, 0.f);
  for (int b0 = 0; b0 < nd.y; b0 += 8) {
    const int myi = b0 + fi;
    int sidx = (myi < nd.y) ? adj[nd.x + myi] : 0;
#pragma unroll
    for (int q = 0; q < 8; q++) {
      if (b0 + q < nd.y) {
        int s = __shfl(sidx, q, 8);
        float4 f = zl4[(size_t)s * 8 + fi];
        acc.x += f.x; acc.y += f.y; acc.z += f.z; acc.w += f.w;
      }
    }
  }
  const float rd = 1.0f / (float)(nd.y > 1 ? nd.y : 1);
  const float4 b4 = *(const float4*)(bsh + fi * 4);
  const float4 sA = *(const float4*)(zr + (size_t)node * 32 + fi * 4);
  float4 o;
  o.x = fmaxf(acc.x * rd + b4.x + sA.x, 0.f);
  o.y = fmaxf(acc.y * rd + b4.y + sA.y, 0.f);
  o.z = fmaxf(acc.z * rd + b4.z + sA.z, 0.f);
  o.w = fmaxf(acc.w * rd + b4.w + sA.w, 0.f);
  *(float4*)(h + (size_t)node * 32 + fi * 4) = o;
}

// ---- kproj2: z2l[n]=h@W2l, z2r[n]=h@W2r (K=32 LDS-tiled GEMM) ------------
__global__ __launch_bounds__(256) void kproj2(
    const float* __restrict__ h, const float* __restrict__ Wl,
    const float* __restrict__ Wr, float* __restrict__ z2l,
    float* __restrict__ z2r, int N) {
  __shared__ __align__(16) float xs[64 * 36];
  __shared__ __align__(16) float ws[32 * 64];
  const int t = threadIdx.x;
  const int n0 = blockIdx.x * 64;
  const int nvalid = (N - n0) < 64 ? (N - n0) : 64;
  const int tx = t & 15, ty = t >> 4;
  const int c0 = tx * 4;
  const int nl = ty * 4;

  for (int i = t; i < 32 * 32; i += 256) {
    int k = i >> 5, c = i & 31;
    ws[k * 64 + c] = Wl[k * 32 + c];
    ws[k * 64 + 32 + c] = Wr[k * 32 + c];
  }
  {
    const int lim = nvalid * 8;  // 8 float4 per node
    for (int i = t; i < lim; i += 256) {
      int n = i >> 3, q = i & 7;
      float4 v = *(const float4*)(h + (size_t)(n0 + n) * 32 + q * 4);
      *(float4*)(xs + n * 36 + q * 4) = v;
    }
  }
  __syncthreads();

  float acc[4][4];
#pragma unroll
  for (int i = 0; i < 4; i++)
#pragma unroll
    for (int j = 0; j < 4; j++) acc[i][j] = 0.f;

  const float* x0 = xs + (nl + 0) * 36;
  const float* x1 = xs + (nl + 1) * 36;
  const float* x2 = xs + (nl + 2) * 36;
  const float* x3 = xs + (nl + 3) * 36;
  for (int k = 0; k < 32; k += 4) {
    float4 xa = *(const float4*)(x0 + k);
    float4 xb = *(const float4*)(x1 + k);
    float4 xc = *(const float4*)(x2 + k);
    float4 xd = *(const float4*)(x3 + k);
#pragma unroll
    for (int kk = 0; kk < 4; kk++) {
      float4 w = *(const float4*)(ws + (k + kk) * 64 + c0);
      float va = ((const float*)&xa)[kk];
      float vb = ((const float*)&xb)[kk];
      float vc = ((const float*)&xc)[kk];
      float vd = ((const float*)&xd)[kk];
      acc[0][0] += va * w.x; acc[0][1] += va * w.y;
      acc[0][2] += va * w.z; acc[0][3] += va * w.w;
      acc[1][0] += vb * w.x; acc[1][1] += vb * w.y;
      acc[1][2] += vb * w.z; acc[1][3] += vb * w.w;
      acc[2][0] += vc * w.x; acc[2][1] += vc * w.y;
      acc[2][2] += vc * w.z; acc[2][3] += vc * w.w;
      acc[3][0] += vd * w.x; acc[3][1] += vd * w.y;
      acc[3][2] += vd * w.z; acc[3][3] += vd * w.w;
    }
  }
#pragma unroll
  for (int i = 0; i < 4; i++) {
    int node = n0 + nl + i;
    if (node < N) {
      float4 v = make_float4(acc[i][0], acc[i][1], acc[i][2], acc[i][3]);
      if (c0 < 32)
        *(float4*)(z2l + (size_t)node * 32 + c0) = v;
      else
        *(float4*)(z2r + (size_t)node * 32 + (c0 - 32)) = v;
    }
  }
}

// ---- fused L2: lean LDS-free gather -> out -------------------------------
__global__ __launch_bounds__(256) void k_fagg2(
    const float* __restrict__ z2l, const float* __restrict__ z2r,
    const int* __restrict__ adj, const int2* __restrict__ nod,
    const float* __restrict__ b2, float* __restrict__ out, int N) {
  __shared__ __align__(16) float bsh[32];
  const int t = threadIdx.x;
  if (t < 32) bsh[t] = b2[t];
  __syncthreads();
  const int g = t >> 3, fi = t & 7;
  const int node = blockIdx.x * 32 + g;
  if (node >= N) return;
  const int2 nd = nod[node];
  const float4* z24 = (const float4*)z2l;
  float4 acc = make_float4(0.f, 0.f, 0.f, 0.f);
  for (int b0 = 0; b0 < nd.y; b0 += 8) {
    const int myi = b0 + fi;
    int sidx = (myi < nd.y) ? adj[nd.x + myi] : 0;
#pragma unroll
    for (int q = 0; q < 8; q++) {
      if (b0 + q < nd.y) {
        int s = __shfl(sidx, q, 8);
        float4 f = z24[(size_t)s * 8 + fi];
        acc.x += f.x; acc.y += f.y; acc.z += f.z; acc.w += f.w;
      }
    }
  }
  const float rd = 1.0f / (float)(nd.y > 1 ? nd.y : 1);
  const float4 b4 = *(const float4*)(bsh + fi * 4);
  const float4 sB = *(const float4*)(z2r + (size_t)node * 32 + fi * 4);
  float4 o;
  o.x = acc.x * rd + b4.x + sB.x;
  o.y = acc.y * rd + b4.y + sB.y;
  o.z = acc.z * rd + b4.z + sB.z;
  o.w = acc.w * rd + b4.w + sB.w;
  *(float4*)(out + (size_t)node * 32 + fi * 4) = o;
}

extern "C" void kernel_launch(void* const* d_in, const int* in_sizes, int n_in,
                              void* d_out, int out_size, void* d_ws,
                              size_t ws_size, hipStream_t stream) {
  const float* x = (const float*)d_in[0];
  const int* ei = (const int*)d_in[1];  // int32 (harness narrows int64)
  const float* W1l = (const float*)d_in[2];
  const float* b1 = (const float*)d_in[3];
  const float* W1r = (const float*)d_in[4];
  const float* W2l = (const float*)d_in[5];
  const float* b2 = (const float*)d_in[6];
  const float* W2r = (const float*)d_in[7];
  float* out = (float*)d_out;

  const int N = N_NODES;
  const int E = in_sizes[1] / 2;  // 800000

  float* zl = (float*)d_ws;                    // N*32
  float* zr = zl + (size_t)N * 32;             // N*32
  float* z2l = zr + (size_t)N * 32;            // N*32
  float* z2r = z2l + (size_t)N * 32;           // N*32
  int* ebuf = (int*)(z2r + (size_t)N * 32);    // NB*CAPE (adj after k_sort)
  int* gcnt = ebuf + (size_t)NB * CAPE;        // NB*32 (one line per bucket)
  int2* nod = (int2*)(gcnt + (size_t)NB * 32); // N
  float* h = out;                              // d_out reused as h[N][32]

  const int* srcp = ei;
  const int* dstp = ei + E;

  const int nblk_proj = (N + 63) / 64;  // 782
  const int nblk_f = (N + 31) / 32;     // 1563

  hipMemsetAsync(gcnt, 0, (size_t)NB * 32 * sizeof(int), stream);
  k_front<<<GB + nblk_proj, 256, 0, stream>>>(x, W1l, W1r, zl, zr, N, 128,
                                              srcp, dstp, gcnt, ebuf, E);
  k_sort<<<NB, 256, 0, stream>>>(ebuf, gcnt, nod, N);
  k_fagg1<<<nblk_f, 256, 0, stream>>>(zl, zr, ebuf, nod, b1, h, N);
  kproj2<<<nblk_proj, 256, 0, stream>>>(h, W2l, W2r, z2l, z2r, N);
  k_fagg2<<<nblk_f, 256, 0, stream>>>(z2l, z2r, ebuf, nod, b2, out, N);
}